// Round 9
// baseline (2500.750 us; speedup 1.0000x reference)
//
#include <hip/hip_runtime.h>
#include <hip/hip_bf16.h>

#define NG 4
#define ID 128
#define HD 128
#define TH 384      // 3*HD
#define NB 32
#define NT 1000
#define XW (NG*ID)  // 512
#define OW (NG*HD)  // 512
// ws layout (f16 idx): ((g*8+bc)*1000 + t)*1536 + j*12 + gate*4 + bi
// region per (g,bc): 1000*1536 f16 = 3.072 MB; total 32 regions = 98.304 MB.

typedef _Float16 v8h __attribute__((ext_vector_type(8)));
typedef _Float16 v4h __attribute__((ext_vector_type(4)));
typedef __attribute__((ext_vector_type(4))) float v4f;

__device__ __forceinline__ float sigm(float v) {
    return __fdividef(1.f, 1.f + __expf(-v));
}
__device__ __forceinline__ float tanh_(float v) {
    v = fminf(fmaxf(v, -15.f), 15.f);
    float e2 = __expf(2.f * v);
    return __fdividef(e2 - 1.f, e2 + 1.f);
}
__device__ __forceinline__ ushort f2h(float x) {
    _Float16 h = (_Float16)x;
    return __builtin_bit_cast(unsigned short, h);
}
__device__ __forceinline__ void gl2lds16(const void* g, void* l) {
    __builtin_amdgcn_global_load_lds(
        (const __attribute__((address_space(1))) unsigned int*)g,
        (__attribute__((address_space(3))) unsigned int*)l, 16, 0, 0);
}

// ---------------- Phase 1: gi = x @ w_ih^T + b_ih, f16 MFMA (R4-proven core),
// stores into gate-lane-friendly layout [g,bc][t][j][gate][bi].
// grid (3, 32*8, 4), block 256. Block: b = by>>3, t-tile = by&7 (128 t-rows).
__global__ __launch_bounds__(256) void gi_gemm3(
    const float* __restrict__ x,
    const float* __restrict__ w_ih,
    const float* __restrict__ b_ih,
    _Float16* __restrict__ gi_ws)
{
    const int tid = threadIdx.x;
    const int w   = tid >> 6, l = tid & 63;
    const int lr  = l & 15, lq = l >> 4;
    const int g   = blockIdx.z;
    const int b   = blockIdx.y >> 3;
    const int tt  = blockIdx.y & 7;
    const int n0  = blockIdx.x * 128 + (w >> 1) * 64;   // gate-col base
    const int t0  = tt * 128 + (w & 1) * 64;            // t base for this wave

    v4f acc[4][4];
    #pragma unroll
    for (int mi = 0; mi < 4; ++mi)
        #pragma unroll
        for (int ni = 0; ni < 4; ++ni)
            acc[mi][ni] = (v4f){0.f, 0.f, 0.f, 0.f};

    #pragma unroll
    for (int kf = 0; kf < 4; ++kf) {
        v8h bf[4], af[4];
        #pragma unroll
        for (int ni = 0; ni < 4; ++ni) {
            const float* p = &w_ih[(size_t)(g * TH + n0 + ni * 16 + lr) * ID + kf * 32 + lq * 8];
            float4 f0 = *reinterpret_cast<const float4*>(p);
            float4 f1 = *reinterpret_cast<const float4*>(p + 4);
            v8h v;
            v[0]=(_Float16)f0.x; v[1]=(_Float16)f0.y; v[2]=(_Float16)f0.z; v[3]=(_Float16)f0.w;
            v[4]=(_Float16)f1.x; v[5]=(_Float16)f1.y; v[6]=(_Float16)f1.z; v[7]=(_Float16)f1.w;
            bf[ni] = v;
        }
        #pragma unroll
        for (int mi = 0; mi < 4; ++mi) {
            int trow = t0 + mi * 16 + lr;
            int tl = trow < NT ? trow : NT - 1;           // clamp (tt==7 tail)
            const float* p = &x[((size_t)b * NT + tl) * XW + g * ID + kf * 32 + lq * 8];
            float4 f0 = *reinterpret_cast<const float4*>(p);
            float4 f1 = *reinterpret_cast<const float4*>(p + 4);
            v8h v;
            v[0]=(_Float16)f0.x; v[1]=(_Float16)f0.y; v[2]=(_Float16)f0.z; v[3]=(_Float16)f0.w;
            v[4]=(_Float16)f1.x; v[5]=(_Float16)f1.y; v[6]=(_Float16)f1.z; v[7]=(_Float16)f1.w;
            af[mi] = v;
        }
        #pragma unroll
        for (int mi = 0; mi < 4; ++mi)
            #pragma unroll
            for (int ni = 0; ni < 4; ++ni)
                acc[mi][ni] = __builtin_amdgcn_mfma_f32_16x16x32_f16(
                    af[mi], bf[ni], acc[mi][ni], 0, 0, 0);
    }

    const size_t rbase = (size_t)(g * 8 + (b >> 2)) * NT;   // region row base
    const int bi = b & 3;
    #pragma unroll
    for (int ni = 0; ni < 4; ++ni) {
        const int col = n0 + ni * 16 + lr;
        const float bias = b_ih[g * TH + col];
        const int gate = col >> 7, jj = col & 127;
        #pragma unroll
        for (int mi = 0; mi < 4; ++mi) {
            #pragma unroll
            for (int r = 0; r < 4; ++r) {
                const int t = t0 + mi * 16 + lq * 4 + r;
                if (t < NT)
                    gi_ws[(rbase + t) * 1536 + jj * 12 + gate * 4 + bi] =
                        (_Float16)(acc[mi][ni][r] + bias);
            }
        }
    }
}

// ---------------- Phase 2: 2-group software-pipelined MFMA recurrence.
// grid 16 (g, pair of 4-batch groups), block 512 (8 waves).
// Phase alpha: MFMA_A(t) || gates_B(t-1); phase beta: MFMA_B(t) || gates_A(t).
// mfma(h_frag, w_frag) => D[batch][j]: gates read gh straight from acc regs.
__global__ __launch_bounds__(512, 1) void gru_rec7(
    const _Float16* __restrict__ gi_ws,
    const float* __restrict__ w_hh,
    const float* __restrict__ b_hh,
    float* __restrict__ out)
{
    __shared__ __align__(16) ushort h_lds[2][16][152];        // [group][batchrow][k pad]
    __shared__ __align__(16) _Float16 tile[3][2][8][1536];    // [ring][group][t][j*12+gate*4+bi]

    const int tid = threadIdx.x;
    const int w = tid >> 6, l = tid & 63;
    const int lr = l & 15, lq = l >> 4;
    const int g    = blockIdx.x & 3;
    const int pair = blockIdx.x >> 2;
    const int bc0  = pair * 2;

    // ---- w_hh B-frags (f16), once: wf[gate][kf], col j = 16w+lr (R7-proven rows)
    v8h wf[3][4];
    #pragma unroll
    for (int i = 0; i < 3; ++i) {
        const int mrow = i * 128 + 16 * w + lr;
        #pragma unroll
        for (int kf = 0; kf < 4; ++kf) {
            const float* p = &w_hh[(size_t)(g * TH + mrow) * HD + kf * 32 + lq * 8];
            float4 f0 = *reinterpret_cast<const float4*>(p);
            float4 f1 = *reinterpret_cast<const float4*>(p + 4);
            v8h v;
            v[0]=(_Float16)f0.x; v[1]=(_Float16)f0.y; v[2]=(_Float16)f0.z; v[3]=(_Float16)f0.w;
            v[4]=(_Float16)f1.x; v[5]=(_Float16)f1.y; v[6]=(_Float16)f1.z; v[7]=(_Float16)f1.w;
            wf[i][kf] = v;
        }
    }

    // ---- gate-lane constants (meaningful for l<16): j = 16w + l
    const int jl = l & 15;
    const int j  = 16 * w + jl;
    const float bR = b_hh[g * TH + j];
    const float bZ = b_hh[g * TH + 128 + j];
    const float bN = b_hh[g * TH + 256 + j];
    float hpA[4] = {0.f,0.f,0.f,0.f}, hpB[4] = {0.f,0.f,0.f,0.f};
    float obA[8][4], obB[8][4];
    v4f accB0 = {0.f,0.f,0.f,0.f}, accB1 = accB0, accB2 = accB0;

    // ---- zero h (rows 4-15 stay zero forever)
    for (int i = tid; i < 2 * 16 * 152 / 2; i += 512)
        reinterpret_cast<unsigned int*>(h_lds)[i] = 0u;

    // ---- DMA stage: 48KB/tile = 2 groups x 3 chunks x 512 thr x 16B
    auto stage = [&](_Float16* dst, int Tt) {
        #pragma unroll
        for (int gs = 0; gs < 2; ++gs) {
            const _Float16* src = gi_ws +
                ((size_t)((g * 8 + bc0 + gs)) * NT + (size_t)Tt * 8) * 1536 + (size_t)tid * 8;
            _Float16* d = dst + gs * 12288 + tid * 8;
            #pragma unroll
            for (int c = 0; c < 3; ++c)
                gl2lds16(src + c * 4096, d + c * 4096);
        }
    };

    stage(&tile[0][0][0][0], 0);
    __syncthreads();

    _Float16* cur = &tile[0][0][0][0];
    _Float16* nxt = &tile[1][0][0][0];
    _Float16* prv = &tile[2][0][0][0];

#define MMA(GS, A0, A1, A2)                                                      \
    {                                                                            \
        const char* hb = reinterpret_cast<const char*>(&h_lds[GS][0][0])         \
                         + lr * 304 + lq * 16;                                   \
        v8h f0 = *reinterpret_cast<const v8h*>(hb);                              \
        v8h f1 = *reinterpret_cast<const v8h*>(hb + 64);                         \
        v8h f2 = *reinterpret_cast<const v8h*>(hb + 128);                        \
        v8h f3 = *reinterpret_cast<const v8h*>(hb + 192);                        \
        A0 = __builtin_amdgcn_mfma_f32_16x16x32_f16(f0, wf[0][0], A0, 0, 0, 0);  \
        A1 = __builtin_amdgcn_mfma_f32_16x16x32_f16(f0, wf[1][0], A1, 0, 0, 0);  \
        A2 = __builtin_amdgcn_mfma_f32_16x16x32_f16(f0, wf[2][0], A2, 0, 0, 0);  \
        A0 = __builtin_amdgcn_mfma_f32_16x16x32_f16(f1, wf[0][1], A0, 0, 0, 0);  \
        A1 = __builtin_amdgcn_mfma_f32_16x16x32_f16(f1, wf[1][1], A1, 0, 0, 0);  \
        A2 = __builtin_amdgcn_mfma_f32_16x16x32_f16(f1, wf[2][1], A2, 0, 0, 0);  \
        A0 = __builtin_amdgcn_mfma_f32_16x16x32_f16(f2, wf[0][2], A0, 0, 0, 0);  \
        A1 = __builtin_amdgcn_mfma_f32_16x16x32_f16(f2, wf[1][2], A1, 0, 0, 0);  \
        A2 = __builtin_amdgcn_mfma_f32_16x16x32_f16(f2, wf[2][2], A2, 0, 0, 0);  \
        A0 = __builtin_amdgcn_mfma_f32_16x16x32_f16(f3, wf[0][3], A0, 0, 0, 0);  \
        A1 = __builtin_amdgcn_mfma_f32_16x16x32_f16(f3, wf[1][3], A1, 0, 0, 0);  \
        A2 = __builtin_amdgcn_mfma_f32_16x16x32_f16(f3, wf[2][3], A2, 0, 0, 0);  \
    }

#define GATES(A0, A1, A2, HP, OBROW, GS, GB)                                     \
    if (l < 16) {                                                                \
        const _Float16* gp = (GB) + j * 12;                                      \
        v4h hR = *reinterpret_cast<const v4h*>(gp);                              \
        v4h hZ = *reinterpret_cast<const v4h*>(gp + 4);                          \
        v4h hN = *reinterpret_cast<const v4h*>(gp + 8);                          \
        _Pragma("unroll")                                                        \
        for (int r = 0; r < 4; ++r) {                                            \
            float rr = sigm((float)hR[r] + (A0)[r] + bR);                        \
            float zz = sigm((float)hZ[r] + (A1)[r] + bZ);                        \
            float nn = tanh_((float)hN[r] + rr * ((A2)[r] + bN));                \
            float hn = fmaf(zz, (HP)[r] - nn, nn);                               \
            (HP)[r] = hn;                                                        \
            (OBROW)[r] = hn;                                                     \
            h_lds[GS][r][j] = f2h(hn);                                           \
        }                                                                        \
    }

    for (int T = 0; T < 125; ++T) {
        if (T < 124) stage(nxt, T + 1);
        #pragma unroll
        for (int kk = 0; kk < 8; ++kk) {
            // ---- phase alpha: MFMA_A(8T+kk); gates_B(8T+kk-1)
            v4f accA0 = {0.f,0.f,0.f,0.f}, accA1 = accA0, accA2 = accA0;
            MMA(0, accA0, accA1, accA2)
            if (kk > 0) {
                const _Float16* gb = cur + 12288 + (kk - 1) * 1536;
                GATES(accB0, accB1, accB2, hpB, obB[kk], 1, gb)
            } else if (T > 0) {
                const _Float16* gb = prv + 12288 + 7 * 1536;
                GATES(accB0, accB1, accB2, hpB, obB[0], 1, gb)
            }
            __syncthreads();
            // ---- phase beta: MFMA_B(8T+kk); gates_A(8T+kk)
            accB0 = (v4f){0.f,0.f,0.f,0.f}; accB1 = accB0; accB2 = accB0;
            MMA(1, accB0, accB1, accB2)
            {
                const _Float16* ga = cur + kk * 1536;
                GATES(accA0, accA1, accA2, hpA, obA[kk], 0, ga)
            }
            __syncthreads();
        }
        // ---- flush output buffers (stores drain at next tile's first barrier)
        if (l < 16) {
            #pragma unroll
            for (int k2 = 0; k2 < 8; ++k2) {
                #pragma unroll
                for (int r = 0; r < 4; ++r) {
                    const size_t tA = (size_t)T * 8 + k2;
                    out[((size_t)(pair * 8 + r) * NT + tA) * OW + g * HD + j] = obA[k2][r];
                    if (T > 0 || k2 > 0)
                        out[((size_t)(pair * 8 + 4 + r) * NT + tA - 1) * OW + g * HD + j] = obB[k2][r];
                }
            }
        }
        _Float16* tmp = prv; prv = cur; cur = nxt; nxt = tmp;
    }
    // ---- epilogue: gates_B(999); after final rotation, tile 124 is in prv
    if (l < 16) {
        const _Float16* gp = prv + 12288 + 7 * 1536 + j * 12;
        v4h hR = *reinterpret_cast<const v4h*>(gp);
        v4h hZ = *reinterpret_cast<const v4h*>(gp + 4);
        v4h hN = *reinterpret_cast<const v4h*>(gp + 8);
        #pragma unroll
        for (int r = 0; r < 4; ++r) {
            float rr = sigm((float)hR[r] + accB0[r] + bR);
            float zz = sigm((float)hZ[r] + accB1[r] + bZ);
            float nn = tanh_((float)hN[r] + rr * (accB2[r] + bN));
            float hn = fmaf(zz, hpB[r] - nn, nn);
            out[((size_t)(pair * 8 + 4 + r) * NT + (NT - 1)) * OW + g * HD + j] = hn;
        }
    }
#undef MMA
#undef GATES
}

extern "C" void kernel_launch(void* const* d_in, const int* in_sizes, int n_in,
                              void* d_out, int out_size, void* d_ws, size_t ws_size,
                              hipStream_t stream) {
    const float* x    = (const float*)d_in[0];
    const float* w_ih = (const float*)d_in[1];
    const float* w_hh = (const float*)d_in[2];
    const float* b_ih = (const float*)d_in[3];
    const float* b_hh = (const float*)d_in[4];
    float* out = (float*)d_out;
    _Float16* gi_ws = (_Float16*)d_ws;   // 98.304 MB layout above

    dim3 g1(3, NB * 8, NG);
    gi_gemm3<<<g1, 256, 0, stream>>>(x, w_ih, b_ih, gi_ws);
    gru_rec7<<<16, 512, 0, stream>>>(gi_ws, w_hh, b_hh, out);
}

// Round 10
// 581.421 us; speedup vs baseline: 4.3011x; 4.3011x over previous
//
#include <hip/hip_runtime.h>
#include <hip/hip_bf16.h>

#define NG 4
#define ID 128
#define HD 128
#define TH 384      // 3*HD
#define NB 32
#define NT 1000
#define XW (NG*ID)  // 512
#define OW (NG*HD)  // 512
// gi_ws layout, f16 units, per (b,g) region of NT*384:
//   t*384 + j*2     : r-gate (lo) | t*384 + j*2+1 : z-gate (hi)  (u32 pair)
//   t*384 + 256 + j : n-gate
// total 128 regions * 768KB = 98.304 MB.

typedef _Float16 v8h __attribute__((ext_vector_type(8)));
typedef __attribute__((ext_vector_type(4))) float v4f;

__device__ __forceinline__ float sigm(float v) {
    return __fdividef(1.f, 1.f + __expf(-v));
}
__device__ __forceinline__ float tanh_(float v) {
    v = fminf(fmaxf(v, -15.f), 15.f);
    float e2 = __expf(2.f * v);
    return __fdividef(e2 - 1.f, e2 + 1.f);
}
__device__ __forceinline__ float sel4(v4f a, int s) {
    float x01 = (s & 1) ? a[1] : a[0];
    float x23 = (s & 1) ? a[3] : a[2];
    return (s & 2) ? x23 : x01;
}
__device__ __forceinline__ void gl2lds16(const void* g, void* l) {
    __builtin_amdgcn_global_load_lds(
        (const __attribute__((address_space(1))) unsigned int*)g,
        (__attribute__((address_space(3))) unsigned int*)l, 16, 0, 0);
}

// ---------------- Phase 1: gi = x @ w_ih^T + b_ih (R4/R9-proven core),
// scattered into the phase-2-friendly layout above.
// grid (3, 256, 4) [gate, b*8+ttile, g], block 256.
__global__ __launch_bounds__(256) void gi_gemm4(
    const float* __restrict__ x,
    const float* __restrict__ w_ih,
    const float* __restrict__ b_ih,
    _Float16* __restrict__ gi_ws)
{
    const int tid = threadIdx.x;
    const int w   = tid >> 6, l = tid & 63;
    const int lr  = l & 15, lq = l >> 4;
    const int g   = blockIdx.z;
    const int b   = blockIdx.y >> 3;
    const int tt  = blockIdx.y & 7;
    const int gate = blockIdx.x;                        // block covers one gate
    const int n0  = gate * 128 + (w >> 1) * 64;
    const int t0  = tt * 128 + (w & 1) * 64;

    v4f acc[4][4];
    #pragma unroll
    for (int mi = 0; mi < 4; ++mi)
        #pragma unroll
        for (int ni = 0; ni < 4; ++ni)
            acc[mi][ni] = (v4f){0.f, 0.f, 0.f, 0.f};

    #pragma unroll
    for (int kf = 0; kf < 4; ++kf) {
        v8h bf[4], af[4];
        #pragma unroll
        for (int ni = 0; ni < 4; ++ni) {
            const float* p = &w_ih[(size_t)(g * TH + n0 + ni * 16 + lr) * ID + kf * 32 + lq * 8];
            float4 f0 = *reinterpret_cast<const float4*>(p);
            float4 f1 = *reinterpret_cast<const float4*>(p + 4);
            v8h v;
            v[0]=(_Float16)f0.x; v[1]=(_Float16)f0.y; v[2]=(_Float16)f0.z; v[3]=(_Float16)f0.w;
            v[4]=(_Float16)f1.x; v[5]=(_Float16)f1.y; v[6]=(_Float16)f1.z; v[7]=(_Float16)f1.w;
            bf[ni] = v;
        }
        #pragma unroll
        for (int mi = 0; mi < 4; ++mi) {
            int trow = t0 + mi * 16 + lr;
            int tl = trow < NT ? trow : NT - 1;
            const float* p = &x[((size_t)b * NT + tl) * XW + g * ID + kf * 32 + lq * 8];
            float4 f0 = *reinterpret_cast<const float4*>(p);
            float4 f1 = *reinterpret_cast<const float4*>(p + 4);
            v8h v;
            v[0]=(_Float16)f0.x; v[1]=(_Float16)f0.y; v[2]=(_Float16)f0.z; v[3]=(_Float16)f0.w;
            v[4]=(_Float16)f1.x; v[5]=(_Float16)f1.y; v[6]=(_Float16)f1.z; v[7]=(_Float16)f1.w;
            af[mi] = v;
        }
        #pragma unroll
        for (int mi = 0; mi < 4; ++mi)
            #pragma unroll
            for (int ni = 0; ni < 4; ++ni)
                acc[mi][ni] = __builtin_amdgcn_mfma_f32_16x16x32_f16(
                    af[mi], bf[ni], acc[mi][ni], 0, 0, 0);
    }

    const size_t rbase = (size_t)(b * NG + g) * NT;
    #pragma unroll
    for (int ni = 0; ni < 4; ++ni) {
        const int col = n0 + ni * 16 + lr;
        const float bias = b_ih[g * TH + col];
        const int jj = col & 127;
        const int off = (gate == 0) ? jj * 2 : (gate == 1) ? jj * 2 + 1 : 256 + jj;
        #pragma unroll
        for (int mi = 0; mi < 4; ++mi) {
            #pragma unroll
            for (int r = 0; r < 4; ++r) {
                const int t = t0 + mi * 16 + lq * 4 + r;
                if (t < NT)
                    gi_ws[(rbase + t) * 384 + off] = (_Float16)(acc[mi][ni][r] + bias);
            }
        }
    }
}

// ---------------- Phase 2: 1 sequence/WG (grid 128), 8 waves, broadcast-B MFMA.
// Wave w: j in [16w,16w+16), all 3 gates. h[128] f16 broadcast; D rows land in
// ALL lanes' accs => gates 1 elem/lane via reg-select, zero cross-lane moves.
__global__ __launch_bounds__(512) void gru_rec8(
    const _Float16* __restrict__ gi_ws,
    const float* __restrict__ w_hh,
    const float* __restrict__ b_hh,
    float* __restrict__ out)
{
    __shared__ __align__(16) _Float16 h_lds[2][128];
    __shared__ __align__(16) _Float16 tile[2][3072];   // 8 t x 384

    const int tid = threadIdx.x;
    const int w = tid >> 6, l = tid & 63;
    const int lr = l & 15, lq = l >> 4;
    const int g = blockIdx.x & 3;
    const int b = blockIdx.x >> 2;

    // ---- w_hh A-frags (R7-proven): a[i][kf], rows i*128 + 16w + lr
    v8h a[3][4];
    #pragma unroll
    for (int i = 0; i < 3; ++i) {
        const int mrow = i * 128 + 16 * w + lr;
        #pragma unroll
        for (int kf = 0; kf < 4; ++kf) {
            const float* p = &w_hh[(size_t)(g * TH + mrow) * HD + kf * 32 + lq * 8];
            float4 f0 = *reinterpret_cast<const float4*>(p);
            float4 f1 = *reinterpret_cast<const float4*>(p + 4);
            v8h v;
            v[0]=(_Float16)f0.x; v[1]=(_Float16)f0.y; v[2]=(_Float16)f0.z; v[3]=(_Float16)f0.w;
            v[4]=(_Float16)f1.x; v[5]=(_Float16)f1.y; v[6]=(_Float16)f1.z; v[7]=(_Float16)f1.w;
            a[i][kf] = v;
        }
    }

    // ---- gate identity: j = 16w + 4*lq + (l&3); 4 redundant copies ((l>>2)&3)
    const int sel = l & 3;
    const int j   = 16 * w + 4 * lq + sel;
    const bool active = ((l >> 2) & 3) == 0;
    // biases as acc-init vectors: reg r = b_hh[gate][16w + 4lq + r]
    const v4f bv0 = *reinterpret_cast<const v4f*>(&b_hh[g * TH +       16 * w + 4 * lq]);
    const v4f bv1 = *reinterpret_cast<const v4f*>(&b_hh[g * TH + 128 + 16 * w + 4 * lq]);
    const v4f bv2 = *reinterpret_cast<const v4f*>(&b_hh[g * TH + 256 + 16 * w + 4 * lq]);
    float hprev = 0.f;
    float* outp = out + (size_t)b * NT * OW + g * HD + j;

    if (tid < 128) { h_lds[0][tid] = (_Float16)0.f; h_lds[1][tid] = (_Float16)0.f; }

    const _Float16* gsrc = gi_ws + (size_t)(b * NG + g) * NT * 384;
    // prologue: tile 0 -> buf 0
    if (tid < 384) gl2lds16(gsrc + tid * 8, &tile[0][tid * 8]);
    __syncthreads();

    float hv[8];
    for (int T = 0; T < 125; ++T) {
        const int cbuf = T & 1;
        if (T < 124 && tid < 384)
            gl2lds16(gsrc + (size_t)(T + 1) * 3072 + tid * 8, &tile[cbuf ^ 1][tid * 8]);
        #pragma unroll
        for (int k = 0; k < 8; ++k) {
            // ---- broadcast B-frags: address ignores lr => identical cols
            const char* hb = reinterpret_cast<const char*>(&h_lds[k & 1][0]) + lq * 16;
            v8h f0 = *reinterpret_cast<const v8h*>(hb);
            v8h f1 = *reinterpret_cast<const v8h*>(hb + 64);
            v8h f2 = *reinterpret_cast<const v8h*>(hb + 128);
            v8h f3 = *reinterpret_cast<const v8h*>(hb + 192);
            v4f ac0 = bv0, ac1 = bv1, ac2 = bv2;
            ac0 = __builtin_amdgcn_mfma_f32_16x16x32_f16(a[0][0], f0, ac0, 0, 0, 0);
            ac1 = __builtin_amdgcn_mfma_f32_16x16x32_f16(a[1][0], f0, ac1, 0, 0, 0);
            ac2 = __builtin_amdgcn_mfma_f32_16x16x32_f16(a[2][0], f0, ac2, 0, 0, 0);
            ac0 = __builtin_amdgcn_mfma_f32_16x16x32_f16(a[0][1], f1, ac0, 0, 0, 0);
            ac1 = __builtin_amdgcn_mfma_f32_16x16x32_f16(a[1][1], f1, ac1, 0, 0, 0);
            ac2 = __builtin_amdgcn_mfma_f32_16x16x32_f16(a[2][1], f1, ac2, 0, 0, 0);
            ac0 = __builtin_amdgcn_mfma_f32_16x16x32_f16(a[0][2], f2, ac0, 0, 0, 0);
            ac1 = __builtin_amdgcn_mfma_f32_16x16x32_f16(a[1][2], f2, ac1, 0, 0, 0);
            ac2 = __builtin_amdgcn_mfma_f32_16x16x32_f16(a[2][2], f2, ac2, 0, 0, 0);
            ac0 = __builtin_amdgcn_mfma_f32_16x16x32_f16(a[0][3], f3, ac0, 0, 0, 0);
            ac1 = __builtin_amdgcn_mfma_f32_16x16x32_f16(a[1][3], f3, ac1, 0, 0, 0);
            ac2 = __builtin_amdgcn_mfma_f32_16x16x32_f16(a[2][3], f3, ac2, 0, 0, 0);

            // ---- in-register gate extraction (3 cndmask each; bias included)
            float ghr = sel4(ac0, sel);
            float ghz = sel4(ac1, sel);
            float ghn = sel4(ac2, sel);

            // ---- gi reads: (r,z) u32 pair + n u16
            const char* gl = reinterpret_cast<const char*>(&tile[cbuf][k * 384]);
            unsigned int rz = *reinterpret_cast<const unsigned int*>(gl + j * 4);
            float iN = (float)*reinterpret_cast<const _Float16*>(gl + 512 + j * 2);
            float iR = (float)__builtin_bit_cast(_Float16, (unsigned short)(rz & 0xffff));
            float iZ = (float)__builtin_bit_cast(_Float16, (unsigned short)(rz >> 16));

            float rr = sigm(iR + ghr);
            float zz = sigm(iZ + ghz);
            float nn = tanh_(fmaf(rr, ghn, iN));
            float hn = fmaf(zz, hprev - nn, nn);
            hprev = hn;
            hv[k] = hn;
            if (active) h_lds[(k + 1) & 1][j] = (_Float16)hn;
            __syncthreads();
        }
        if (active) {
            const size_t ob = (size_t)(T * 8) * OW;
            #pragma unroll
            for (int k = 0; k < 8; ++k)
                outp[ob + (size_t)k * OW] = hv[k];
        }
    }
}

extern "C" void kernel_launch(void* const* d_in, const int* in_sizes, int n_in,
                              void* d_out, int out_size, void* d_ws, size_t ws_size,
                              hipStream_t stream) {
    const float* x    = (const float*)d_in[0];
    const float* w_ih = (const float*)d_in[1];
    const float* w_hh = (const float*)d_in[2];
    const float* b_ih = (const float*)d_in[3];
    const float* b_hh = (const float*)d_in[4];
    float* out = (float*)d_out;
    _Float16* gi_ws = (_Float16*)d_ws;   // 98.304 MB, layout above

    dim3 g1(3, NB * 8, NG);
    gi_gemm4<<<g1, 256, 0, stream>>>(x, w_ih, b_ih, gi_ws);
    gru_rec8<<<NB * NG, 512, 0, stream>>>(gi_ws, w_hh, b_hh, out);
}

// Round 11
// 555.776 us; speedup vs baseline: 4.4996x; 1.0461x over previous
//
#include <hip/hip_runtime.h>
#include <hip/hip_bf16.h>

#define NG 4
#define ID 128
#define HD 128
#define TH 384      // 3*HD
#define NB 32
#define NT 1000
#define XW (NG*ID)  // 512
#define OW (NG*HD)  // 512
// gi_ws layout, f16 units, per (b,g) region of NT*384:
//   t*384 + j*2     : r-gate (lo) | t*384 + j*2+1 : z-gate (hi)  (u32 pair)
//   t*384 + 256 + j : n-gate
// total 128 regions * 768KB = 98.304 MB.

typedef _Float16 v8h __attribute__((ext_vector_type(8)));
typedef __attribute__((ext_vector_type(4))) float v4f;

__device__ __forceinline__ float sigm(float v) {
    return __fdividef(1.f, 1.f + __expf(-v));
}
__device__ __forceinline__ float tanh_(float v) {
    v = fminf(fmaxf(v, -15.f), 15.f);
    float e2 = __expf(2.f * v);
    return __fdividef(e2 - 1.f, e2 + 1.f);
}
__device__ __forceinline__ float sel4(v4f a, int s) {
    float x01 = (s & 1) ? a[1] : a[0];
    float x23 = (s & 1) ? a[3] : a[2];
    return (s & 2) ? x23 : x01;
}

// ---------------- Phase 1 (R10-proven, unchanged): gi = x @ w_ih^T + b_ih.
// grid (3, 256, 4) [gate, b*8+ttile, g], block 256.
__global__ __launch_bounds__(256) void gi_gemm4(
    const float* __restrict__ x,
    const float* __restrict__ w_ih,
    const float* __restrict__ b_ih,
    _Float16* __restrict__ gi_ws)
{
    const int tid = threadIdx.x;
    const int w   = tid >> 6, l = tid & 63;
    const int lr  = l & 15, lq = l >> 4;
    const int g   = blockIdx.z;
    const int b   = blockIdx.y >> 3;
    const int tt  = blockIdx.y & 7;
    const int gate = blockIdx.x;
    const int n0  = gate * 128 + (w >> 1) * 64;
    const int t0  = tt * 128 + (w & 1) * 64;

    v4f acc[4][4];
    #pragma unroll
    for (int mi = 0; mi < 4; ++mi)
        #pragma unroll
        for (int ni = 0; ni < 4; ++ni)
            acc[mi][ni] = (v4f){0.f, 0.f, 0.f, 0.f};

    #pragma unroll
    for (int kf = 0; kf < 4; ++kf) {
        v8h bf[4], af[4];
        #pragma unroll
        for (int ni = 0; ni < 4; ++ni) {
            const float* p = &w_ih[(size_t)(g * TH + n0 + ni * 16 + lr) * ID + kf * 32 + lq * 8];
            float4 f0 = *reinterpret_cast<const float4*>(p);
            float4 f1 = *reinterpret_cast<const float4*>(p + 4);
            v8h v;
            v[0]=(_Float16)f0.x; v[1]=(_Float16)f0.y; v[2]=(_Float16)f0.z; v[3]=(_Float16)f0.w;
            v[4]=(_Float16)f1.x; v[5]=(_Float16)f1.y; v[6]=(_Float16)f1.z; v[7]=(_Float16)f1.w;
            bf[ni] = v;
        }
        #pragma unroll
        for (int mi = 0; mi < 4; ++mi) {
            int trow = t0 + mi * 16 + lr;
            int tl = trow < NT ? trow : NT - 1;
            const float* p = &x[((size_t)b * NT + tl) * XW + g * ID + kf * 32 + lq * 8];
            float4 f0 = *reinterpret_cast<const float4*>(p);
            float4 f1 = *reinterpret_cast<const float4*>(p + 4);
            v8h v;
            v[0]=(_Float16)f0.x; v[1]=(_Float16)f0.y; v[2]=(_Float16)f0.z; v[3]=(_Float16)f0.w;
            v[4]=(_Float16)f1.x; v[5]=(_Float16)f1.y; v[6]=(_Float16)f1.z; v[7]=(_Float16)f1.w;
            af[mi] = v;
        }
        #pragma unroll
        for (int mi = 0; mi < 4; ++mi)
            #pragma unroll
            for (int ni = 0; ni < 4; ++ni)
                acc[mi][ni] = __builtin_amdgcn_mfma_f32_16x16x32_f16(
                    af[mi], bf[ni], acc[mi][ni], 0, 0, 0);
    }

    const size_t rbase = (size_t)(b * NG + g) * NT;
    #pragma unroll
    for (int ni = 0; ni < 4; ++ni) {
        const int col = n0 + ni * 16 + lr;
        const float bias = b_ih[g * TH + col];
        const int jj = col & 127;
        const int off = (gate == 0) ? jj * 2 : (gate == 1) ? jj * 2 + 1 : 256 + jj;
        #pragma unroll
        for (int mi = 0; mi < 4; ++mi) {
            #pragma unroll
            for (int r = 0; r < 4; ++r) {
                const int t = t0 + mi * 16 + lq * 4 + r;
                if (t < NT)
                    gi_ws[(rbase + t) * 384 + off] = (_Float16)(acc[mi][ni][r] + bias);
            }
        }
    }
}

// ---------------- Phase 2: broadcast-B MFMA recurrence (R10 math, new sync).
// grid 128 (1 seq/WG), 8 waves. Raw s_barrier + lgkmcnt(0) per step; vmcnt
// never drained in-loop. gi read global->reg with 2-step-ahead prefetch.
__global__ __launch_bounds__(512) void gru_rec9(
    const _Float16* __restrict__ gi_ws,
    const float* __restrict__ w_hh,
    const float* __restrict__ b_hh,
    float* __restrict__ out)
{
    __shared__ __align__(16) _Float16 h_lds[2][128];

    const int tid = threadIdx.x;
    const int w = tid >> 6, l = tid & 63;
    const int lr = l & 15, lq = l >> 4;
    const int g = blockIdx.x & 3;
    const int b = blockIdx.x >> 2;

    // ---- w_hh A-frags (R10-proven): a[i][kf], rows i*128 + 16w + lr
    v8h a[3][4];
    #pragma unroll
    for (int i = 0; i < 3; ++i) {
        const int mrow = i * 128 + 16 * w + lr;
        #pragma unroll
        for (int kf = 0; kf < 4; ++kf) {
            const float* p = &w_hh[(size_t)(g * TH + mrow) * HD + kf * 32 + lq * 8];
            float4 f0 = *reinterpret_cast<const float4*>(p);
            float4 f1 = *reinterpret_cast<const float4*>(p + 4);
            v8h v;
            v[0]=(_Float16)f0.x; v[1]=(_Float16)f0.y; v[2]=(_Float16)f0.z; v[3]=(_Float16)f0.w;
            v[4]=(_Float16)f1.x; v[5]=(_Float16)f1.y; v[6]=(_Float16)f1.z; v[7]=(_Float16)f1.w;
            a[i][kf] = v;
        }
    }

    // ---- gate identity (R10-proven): j = 16w + 4*lq + sel; 4 copies, 1 active
    const int sel = l & 3;
    const int j   = 16 * w + 4 * lq + sel;
    const bool active = ((l >> 2) & 3) == 0;
    const v4f bv0 = *reinterpret_cast<const v4f*>(&b_hh[g * TH +       16 * w + 4 * lq]);
    const v4f bv1 = *reinterpret_cast<const v4f*>(&b_hh[g * TH + 128 + 16 * w + 4 * lq]);
    const v4f bv2 = *reinterpret_cast<const v4f*>(&b_hh[g * TH + 256 + 16 * w + 4 * lq]);
    float hprev = 0.f;
    float* outp = out + (size_t)b * NT * OW + g * HD + j;

    if (tid < 128) { h_lds[0][tid] = (_Float16)0.f; h_lds[1][tid] = (_Float16)0.f; }

    const _Float16* gsrc = gi_ws + (size_t)(b * NG + g) * NT * 384;

    // ---- gi reg-ring, 2-step lead: set P holds gi for step t with t&1==P
    unsigned int rz0, rz1;
    _Float16 nv0, nv1;
    {
        const _Float16* g0 = gsrc;               // t = 0
        const _Float16* g1 = gsrc + 384;         // t = 1
        rz0 = *reinterpret_cast<const unsigned int*>(g0 + j * 2);
        nv0 = g0[256 + j];
        rz1 = *reinterpret_cast<const unsigned int*>(g1 + j * 2);
        nv1 = g1[256 + j];
    }
    __syncthreads();   // once; drains prologue loads + LDS zero-init

#define STEP(P, TCUR, RZ, NV)                                                      \
    {                                                                              \
        const char* hb = reinterpret_cast<const char*>(&h_lds[P][0]) + lq * 16;    \
        v8h f0 = *reinterpret_cast<const v8h*>(hb);                                \
        v8h f1 = *reinterpret_cast<const v8h*>(hb + 64);                           \
        v8h f2 = *reinterpret_cast<const v8h*>(hb + 128);                          \
        v8h f3 = *reinterpret_cast<const v8h*>(hb + 192);                          \
        v4f ac0 = bv0, ac1 = bv1, ac2 = bv2;                                       \
        ac0 = __builtin_amdgcn_mfma_f32_16x16x32_f16(a[0][0], f0, ac0, 0, 0, 0);   \
        ac1 = __builtin_amdgcn_mfma_f32_16x16x32_f16(a[1][0], f0, ac1, 0, 0, 0);   \
        ac2 = __builtin_amdgcn_mfma_f32_16x16x32_f16(a[2][0], f0, ac2, 0, 0, 0);   \
        ac0 = __builtin_amdgcn_mfma_f32_16x16x32_f16(a[0][1], f1, ac0, 0, 0, 0);   \
        ac1 = __builtin_amdgcn_mfma_f32_16x16x32_f16(a[1][1], f1, ac1, 0, 0, 0);   \
        ac2 = __builtin_amdgcn_mfma_f32_16x16x32_f16(a[2][1], f1, ac2, 0, 0, 0);   \
        ac0 = __builtin_amdgcn_mfma_f32_16x16x32_f16(a[0][2], f2, ac0, 0, 0, 0);   \
        ac1 = __builtin_amdgcn_mfma_f32_16x16x32_f16(a[1][2], f2, ac1, 0, 0, 0);   \
        ac2 = __builtin_amdgcn_mfma_f32_16x16x32_f16(a[2][2], f2, ac2, 0, 0, 0);   \
        ac0 = __builtin_amdgcn_mfma_f32_16x16x32_f16(a[0][3], f3, ac0, 0, 0, 0);   \
        ac1 = __builtin_amdgcn_mfma_f32_16x16x32_f16(a[1][3], f3, ac1, 0, 0, 0);   \
        ac2 = __builtin_amdgcn_mfma_f32_16x16x32_f16(a[2][3], f3, ac2, 0, 0, 0);   \
        float ghr = sel4(ac0, sel);                                                \
        float ghz = sel4(ac1, sel);                                                \
        float ghn = sel4(ac2, sel);                                                \
        float iR = (float)__builtin_bit_cast(_Float16, (unsigned short)(RZ & 0xffff)); \
        float iZ = (float)__builtin_bit_cast(_Float16, (unsigned short)(RZ >> 16));    \
        float iN = (float)NV;                                                      \
        float rr = sigm(iR + ghr);                                                 \
        float zz = sigm(iZ + ghz);                                                 \
        float nn = tanh_(fmaf(rr, ghn, iN));                                       \
        float hn = fmaf(zz, hprev - nn, nn);                                       \
        hprev = hn;                                                                \
        if (active) {                                                              \
            h_lds[(P) ^ 1][j] = (_Float16)hn;                                      \
            outp[(size_t)(TCUR) * OW] = hn;                                        \
        }                                                                          \
        {   /* prefetch gi for t+2 into the set just freed */                      \
            int tl = (TCUR) + 2 < NT ? (TCUR) + 2 : NT - 1;                        \
            const _Float16* gt = gsrc + (size_t)tl * 384;                          \
            RZ = *reinterpret_cast<const unsigned int*>(gt + j * 2);               \
            NV = gt[256 + j];                                                      \
        }                                                                          \
        asm volatile("s_waitcnt lgkmcnt(0)" ::: "memory");                         \
        __builtin_amdgcn_s_barrier();                                              \
        __builtin_amdgcn_sched_barrier(0);                                         \
    }

    for (int t = 0; t < NT; t += 2) {
        STEP(0, t,     rz0, nv0)
        STEP(1, t + 1, rz1, nv1)
    }
#undef STEP
}

extern "C" void kernel_launch(void* const* d_in, const int* in_sizes, int n_in,
                              void* d_out, int out_size, void* d_ws, size_t ws_size,
                              hipStream_t stream) {
    const float* x    = (const float*)d_in[0];
    const float* w_ih = (const float*)d_in[1];
    const float* w_hh = (const float*)d_in[2];
    const float* b_ih = (const float*)d_in[3];
    const float* b_hh = (const float*)d_in[4];
    float* out = (float*)d_out;
    _Float16* gi_ws = (_Float16*)d_ws;   // 98.304 MB, layout above

    dim3 g1(3, NB * 8, NG);
    gi_gemm4<<<g1, 256, 0, stream>>>(x, w_ih, b_ih, gi_ws);
    gru_rec9<<<NB * NG, 512, 0, stream>>>(gi_ws, w_hh, b_hh, out);
}